// Round 9
// baseline (94.409 us; speedup 1.0000x reference)
//
#include <hip/hip_runtime.h>
#include <stdint.h>

// Problem constants (from the reference)
constexpr int BATCH       = 32;
constexpr int NUM_WINDOWS = 1020;
constexpr int FLAT        = 128;   // num_vars * window_size * k
constexpr int VOCAB_ROWS  = 2048;  // power of two -> mod is a mask
constexpr int EMBED_DIM   = 512;
constexpr unsigned long long BIG_PRIME = 17461204521323ull;

using ull = unsigned long long;
// Native clang vector types: __builtin_nontemporal_* rejects HIP_vector_type
// (a C++ class); ext_vector_type is bit-compatible and accepted.
typedef int   vint4   __attribute__((ext_vector_type(4)));
typedef float vfloat4 __attribute__((ext_vector_type(4)));

// Reference: h=0; for t in flat: h = (h + t + 1) * P   (int64, wrapping)
//   ==> h = sum_{i=0..127} (t_i + 1) * P^(128 - i)   mod 2^64
// (signed wrap == unsigned wrap bitwise; t in [0,32) widens losslessly).
// Precompute P^k mod 2^64 at compile time.
struct Pows { ull v[FLAT + 1]; };
constexpr Pows make_pows() {
    Pows p{};
    p.v[0] = 1ull;
    for (int i = 1; i <= FLAT; ++i) p.v[i] = p.v[i - 1] * BIG_PRIME;
    return p;
}
__constant__ Pows c_pows = make_pows();

// One 64-lane wave per TOKEN PAIR (32640 tokens -> 16320 waves):
//  - lane l loads vint4 at pair_base + 4*l  (16 B/lane, 1 KiB/wave, coalesced;
//    lanes 0-31 cover token A's 128 ints, lanes 32-63 token B's)
//  - 4 mult-adds vs the compile-time power table (wrapping uint64, 4x ILP)
//  - 5-step xor-butterfly (offsets 16..1 keep the 32-lane halves independent:
//    bit 5 of the lane id never flips) -> each half holds its token's h
//  - tok = h & 2047 (floored mod by pow2 == mask on two's complement)
//  - each 32-lane half copies its 512-float row as 4 x float4/lane
//  - fuzz/out are touched exactly once -> nontemporal, keeping the 4 MB
//    embedding table resident in the 4 MiB/XCD L2 for the gathers
__global__ __launch_bounds__(256) void tokenizer_kernel(
    const int* __restrict__ fuzz,
    const float* __restrict__ emb,
    float* __restrict__ out,
    int n_pairs)
{
    const int gtid = blockIdx.x * blockDim.x + threadIdx.x;
    const int pair = gtid >> 6;
    const int lane = threadIdx.x & 63;
    if (pair >= n_pairs) return;

    const int half = lane >> 5;        // 0: token A, 1: token B
    const int j    = lane & 31;        // lane within half
    const int tok_idx = 2 * pair + half;

    const vint4 t = __builtin_nontemporal_load(
        reinterpret_cast<const vint4*>(fuzz + (size_t)pair * (2 * FLAT)) + lane);

    const int e = 4 * j;               // this lane's first element index in its token
    ull h = (ull)(unsigned)(t.x + 1) * c_pows.v[FLAT - e]
          + (ull)(unsigned)(t.y + 1) * c_pows.v[FLAT - e - 1]
          + (ull)(unsigned)(t.z + 1) * c_pows.v[FLAT - e - 2]
          + (ull)(unsigned)(t.w + 1) * c_pows.v[FLAT - e - 3];

    // Butterfly reduce within each 32-lane half (wrapping adds are associative).
    #pragma unroll
    for (int off = 16; off > 0; off >>= 1)
        h += (ull)__shfl_xor((long long)h, off, 64);

    const unsigned tok = (unsigned)(h & (ull)(VOCAB_ROWS - 1));

    const vfloat4* src = reinterpret_cast<const vfloat4*>(emb + (size_t)tok * EMBED_DIM);
    vfloat4*       dst = reinterpret_cast<vfloat4*>(out + (size_t)tok_idx * EMBED_DIM);
    // 512 floats = 128 float4; 32 lanes x 4 each, stride-32 so each group of
    // 32 lanes stores a contiguous 512 B segment.
    #pragma unroll
    for (int k = 0; k < 4; ++k)
        __builtin_nontemporal_store(src[j + 32 * k], dst + j + 32 * k);
}

extern "C" void kernel_launch(void* const* d_in, const int* in_sizes, int n_in,
                              void* d_out, int out_size, void* d_ws, size_t ws_size,
                              hipStream_t stream) {
    const int*   fuzz = (const int*)d_in[0];   // int32 on device (harness narrows int64)
    const float* emb  = (const float*)d_in[1]; // f32 [2048,512]
    float*       out  = (float*)d_out;         // f32 [32,1020,512]

    const int n_tokens = BATCH * NUM_WINDOWS;  // 32640 (even)
    const int n_pairs  = n_tokens / 2;         // 16320 waves
    const int threads  = 256;                  // 4 waves/block
    const int blocks   = (n_pairs * 64 + threads - 1) / threads;  // 4080

    tokenizer_kernel<<<blocks, threads, 0, stream>>>(fuzz, emb, out, n_pairs);
}